// Round 1
// baseline (687.950 us; speedup 1.0000x reference)
//
#include <hip/hip_runtime.h>
#include <math.h>

// ---------------------------------------------------------------------------
// SparseMHA: q/k/v = h@W + b ; s[e,h] = q[row[e],h,:].k[col[e],h,:] ;
// softmax over incoming edges per dst node ; agg = sum attn*v[col] ;
// out = agg @ Wo + bo
// ---------------------------------------------------------------------------

// Tiled f32 GEMM: C[n x 256] = (A[n x 256] @ W[256 x 256] + bias) * scale
// 64x64 tile, 256 threads, each thread 4x4 micro-tile, K-step 16.
__global__ __launch_bounds__(256) void gemm_tile(
    const float* __restrict__ A, const float* __restrict__ W,
    const float* __restrict__ bias, float* __restrict__ C,
    int n, float scale)
{
    __shared__ float As[16][68];  // [k][m], padded for b128 alignment
    __shared__ float Bs[16][68];  // [k][n]
    const int tid = threadIdx.x;
    const int tx = tid & 15, ty = tid >> 4;
    const int row0 = blockIdx.x * 64;
    const int col0 = blockIdx.y * 64;

    float acc[4][4] = {};

    const int lm = tid >> 2;          // 0..63: A row within tile
    const int lk = (tid & 3) << 2;    // 0,4,8,12: A k within tile
    const int bk = tid >> 4;          // 0..15: B k row
    const int bn = (tid & 15) << 2;   // B col within tile

    for (int k0 = 0; k0 < 256; k0 += 16) {
        int ar = row0 + lm;
        float4 av = make_float4(0.f, 0.f, 0.f, 0.f);
        if (ar < n) av = *(const float4*)(A + (size_t)ar * 256 + k0 + lk);
        As[lk + 0][lm] = av.x;
        As[lk + 1][lm] = av.y;
        As[lk + 2][lm] = av.z;
        As[lk + 3][lm] = av.w;

        float4 bv4 = *(const float4*)(W + (size_t)(k0 + bk) * 256 + col0 + bn);
        *(float4*)&Bs[bk][bn] = bv4;
        __syncthreads();

        #pragma unroll
        for (int kk = 0; kk < 16; ++kk) {
            float4 a4 = *(const float4*)&As[kk][ty << 2];
            float4 b4 = *(const float4*)&Bs[kk][tx << 2];
            float a[4] = {a4.x, a4.y, a4.z, a4.w};
            float b[4] = {b4.x, b4.y, b4.z, b4.w};
            #pragma unroll
            for (int i = 0; i < 4; ++i)
                #pragma unroll
                for (int j = 0; j < 4; ++j)
                    acc[i][j] = fmaf(a[i], b[j], acc[i][j]);
        }
        __syncthreads();
    }

    #pragma unroll
    for (int i = 0; i < 4; ++i) {
        int r = row0 + (ty << 2) + i;
        if (r >= n) continue;
        int c = col0 + (tx << 2);
        float4 o;
        o.x = (acc[i][0] + bias[c + 0]) * scale;
        o.y = (acc[i][1] + bias[c + 1]) * scale;
        o.z = (acc[i][2] + bias[c + 2]) * scale;
        o.w = (acc[i][3] + bias[c + 3]) * scale;
        *(float4*)(C + (size_t)r * 256 + c) = o;
    }
}

// CSR row pointers from sorted row[]: row_ptr[i] = lower_bound(row, i)
__global__ __launch_bounds__(256) void build_row_ptr(
    const int* __restrict__ row, int* __restrict__ row_ptr, int n, int E)
{
    int i = blockIdx.x * 256 + threadIdx.x;
    if (i > n) return;
    int lo = 0, hi = E;
    while (lo < hi) {
        int mid = (lo + hi) >> 1;
        if (row[mid] < i) lo = mid + 1; else hi = mid;
    }
    row_ptr[i] = lo;
}

// SDDMM: s[e,h] = dot32(q[row[e],h,:], k[col[e],h,:]); 8 threads per edge.
__global__ __launch_bounds__(256) void edge_scores(
    const float* __restrict__ q, const float* __restrict__ k,
    const int* __restrict__ row, const int* __restrict__ col,
    float* __restrict__ s, int E)
{
    int idx = blockIdx.x * 256 + threadIdx.x;
    int e = idx >> 3;
    if (e >= E) return;
    int h = idx & 7;
    int dst = row[e], src = col[e];
    const float4* qp = (const float4*)(q + (size_t)dst * 256 + h * 32);
    const float4* kp = (const float4*)(k + (size_t)src * 256 + h * 32);
    float acc = 0.f;
    #pragma unroll
    for (int i = 0; i < 8; ++i) {
        float4 a = qp[i], b = kp[i];
        acc += a.x * b.x + a.y * b.y + a.z * b.z + a.w * b.w;
    }
    s[(size_t)e * 8 + h] = acc;
}

// Per-node segment softmax + weighted aggregation of v[col].
// One wave per node: pass1 max (coalesced s reads, lane=(j,h)),
// pass2 exp/denom/acc (coalesced v reads, lane=(h,j)).
__global__ __launch_bounds__(256) void softmax_agg(
    const float* __restrict__ s, const float* __restrict__ v,
    const int* __restrict__ col, const int* __restrict__ row_ptr,
    float* __restrict__ agg, int n)
{
    int node = blockIdx.x * 4 + (threadIdx.x >> 6);
    if (node >= n) return;
    int lane = threadIdx.x & 63;
    int p0 = row_ptr[node], p1 = row_ptr[node + 1];

    // pass 1: max over edges for head (lane&7), edge slot (lane>>3)
    float m = -INFINITY;
    for (int base = p0; base < p1; base += 8) {
        int e = base + (lane >> 3);
        if (e < p1) m = fmaxf(m, s[(size_t)e * 8 + (lane & 7)]);
    }
    m = fmaxf(m, __shfl_xor(m, 8));
    m = fmaxf(m, __shfl_xor(m, 16));
    m = fmaxf(m, __shfl_xor(m, 32));
    // lane now holds max of head (lane&7); pass 2 wants head (lane>>3)
    m = __shfl(m, lane >> 3);

    // pass 2: lane = h*8 + j owns out[node, h, j*4 .. j*4+4)
    int h = lane >> 3, j = lane & 7;
    float denom = 0.f;
    float4 acc = make_float4(0.f, 0.f, 0.f, 0.f);
    for (int e = p0; e < p1; ++e) {
        float p = __expf(s[(size_t)e * 8 + h] - m);
        denom += p;
        int src = col[e];
        float4 vv = *(const float4*)(v + (size_t)src * 256 + h * 32 + (j << 2));
        acc.x = fmaf(p, vv.x, acc.x);
        acc.y = fmaf(p, vv.y, acc.y);
        acc.z = fmaf(p, vv.z, acc.z);
        acc.w = fmaf(p, vv.w, acc.w);
    }
    float inv = denom > 0.f ? 1.f / denom : 0.f;
    float4 o = make_float4(acc.x * inv, acc.y * inv, acc.z * inv, acc.w * inv);
    *(float4*)(agg + (size_t)node * 256 + (lane << 2)) = o;
}

extern "C" void kernel_launch(void* const* d_in, const int* in_sizes, int n_in,
                              void* d_out, int out_size, void* d_ws, size_t ws_size,
                              hipStream_t stream)
{
    const float* h  = (const float*)d_in[0];
    const int*   row = (const int*)d_in[1];
    const int*   col = (const int*)d_in[2];
    const float* Wq = (const float*)d_in[3];
    const float* bq = (const float*)d_in[4];
    const float* Wk = (const float*)d_in[5];
    const float* bk = (const float*)d_in[6];
    const float* Wv = (const float*)d_in[7];
    const float* bv = (const float*)d_in[8];
    const float* Wo = (const float*)d_in[9];
    const float* bo = (const float*)d_in[10];
    float* out = (float*)d_out;

    const int n = in_sizes[0] / 256;
    const int E = in_sizes[1];

    float* ws = (float*)d_ws;
    const size_t NC = (size_t)n * 256;
    float* q = ws;
    float* k = ws + NC;
    float* v = ws + 2 * NC;
    float* s = ws + 3 * NC;
    float* agg = q;  // alias: q is dead after edge_scores
    int* row_ptr = (int*)(ws + 3 * NC + (size_t)E * 8);

    const float scaling = 0.17677669529663687f;  // 32^-0.5

    dim3 gblk(256);
    dim3 ggrid((n + 63) / 64, 4);
    gemm_tile<<<ggrid, gblk, 0, stream>>>(h, Wq, bq, q, n, scaling);
    gemm_tile<<<ggrid, gblk, 0, stream>>>(h, Wk, bk, k, n, 1.f);
    gemm_tile<<<ggrid, gblk, 0, stream>>>(h, Wv, bv, v, n, 1.f);

    build_row_ptr<<<dim3((n + 256) / 256), gblk, 0, stream>>>(row, row_ptr, n, E);

    edge_scores<<<dim3((int)(((size_t)E * 8 + 255) / 256)), gblk, 0, stream>>>(
        q, k, row, col, s, E);

    softmax_agg<<<dim3((n + 3) / 4), gblk, 0, stream>>>(s, v, col, row_ptr, agg, n);

    gemm_tile<<<ggrid, gblk, 0, stream>>>(agg, Wo, bo, out, n, 1.f);
}

// Round 2
// 540.571 us; speedup vs baseline: 1.2726x; 1.2726x over previous
//
#include <hip/hip_runtime.h>
#include <math.h>

// ---------------------------------------------------------------------------
// SparseMHA:
//   q = (h@Wq+bq)*scale (f32) ; k = h@Wk+bk (bf16) ; v = h@Wv+bv (bf16)
//   fused per-dst-node: s[e,h]=q[dst,h,:].k[src,h,:], online softmax,
//                       agg[dst] = sum_e attn[e,h]*v[src,h,:]
//   out = agg @ Wo + bo
// ---------------------------------------------------------------------------

__device__ __forceinline__ ushort f2bf(float f) {           // RNE f32->bf16
    uint u = __float_as_uint(f);
    u += 0x7fffu + ((u >> 16) & 1u);
    return (ushort)(u >> 16);
}
__device__ __forceinline__ float bflo(uint u) { return __uint_as_float(u << 16); }
__device__ __forceinline__ float bfhi(uint u) { return __uint_as_float(u & 0xffff0000u); }

// Tiled f32 GEMM: C[n x 256] = (A[n x 256] @ W[256 x 256] + bias) * scale
// 64x64 tile, 256 threads, 4x4 micro-tile, K-step 16. BF16OUT: pack output.
template<bool BF16OUT>
__global__ __launch_bounds__(256) void gemm_tile(
    const float* __restrict__ A, const float* __restrict__ W,
    const float* __restrict__ bias, void* __restrict__ Cout,
    int n, float scale)
{
    __shared__ float As[16][68];
    __shared__ float Bs[16][68];
    const int tid = threadIdx.x;
    const int tx = tid & 15, ty = tid >> 4;
    const int row0 = blockIdx.x * 64;
    const int col0 = blockIdx.y * 64;

    float acc[4][4] = {};

    const int lm = tid >> 2;
    const int lk = (tid & 3) << 2;
    const int bk = tid >> 4;
    const int bn = (tid & 15) << 2;

    for (int k0 = 0; k0 < 256; k0 += 16) {
        int ar = row0 + lm;
        float4 av = make_float4(0.f, 0.f, 0.f, 0.f);
        if (ar < n) av = *(const float4*)(A + (size_t)ar * 256 + k0 + lk);
        As[lk + 0][lm] = av.x;
        As[lk + 1][lm] = av.y;
        As[lk + 2][lm] = av.z;
        As[lk + 3][lm] = av.w;

        float4 bv4 = *(const float4*)(W + (size_t)(k0 + bk) * 256 + col0 + bn);
        *(float4*)&Bs[bk][bn] = bv4;
        __syncthreads();

        #pragma unroll
        for (int kk = 0; kk < 16; ++kk) {
            float4 a4 = *(const float4*)&As[kk][ty << 2];
            float4 b4 = *(const float4*)&Bs[kk][tx << 2];
            float a[4] = {a4.x, a4.y, a4.z, a4.w};
            float b[4] = {b4.x, b4.y, b4.z, b4.w};
            #pragma unroll
            for (int i = 0; i < 4; ++i)
                #pragma unroll
                for (int j = 0; j < 4; ++j)
                    acc[i][j] = fmaf(a[i], b[j], acc[i][j]);
        }
        __syncthreads();
    }

    #pragma unroll
    for (int i = 0; i < 4; ++i) {
        int r = row0 + (ty << 2) + i;
        if (r >= n) continue;
        int c = col0 + (tx << 2);
        float o0 = (acc[i][0] + bias[c + 0]) * scale;
        float o1 = (acc[i][1] + bias[c + 1]) * scale;
        float o2 = (acc[i][2] + bias[c + 2]) * scale;
        float o3 = (acc[i][3] + bias[c + 3]) * scale;
        if constexpr (BF16OUT) {
            ushort4 o = make_ushort4(f2bf(o0), f2bf(o1), f2bf(o2), f2bf(o3));
            *(ushort4*)((ushort*)Cout + (size_t)r * 256 + c) = o;
        } else {
            *(float4*)((float*)Cout + (size_t)r * 256 + c) =
                make_float4(o0, o1, o2, o3);
        }
    }
}

// CSR row pointers from sorted row[]: row_ptr[i] = lower_bound(row, i)
__global__ __launch_bounds__(256) void build_row_ptr(
    const int* __restrict__ row, int* __restrict__ row_ptr, int n, int E)
{
    int i = blockIdx.x * 256 + threadIdx.x;
    if (i > n) return;
    int lo = 0, hi = E;
    while (lo < hi) {
        int mid = (lo + hi) >> 1;
        if (row[mid] < i) lo = mid + 1; else hi = mid;
    }
    row_ptr[i] = lo;
}

// Fused SDDMM + online softmax + SpMM. One wave per dst node.
// Score phase:  lane = slot*8 + sh  -> s[slot, sh] = q[dst,sh,:].k[src,sh,:]
// Accum phase:  lane = ah*8 + aj    -> acc = out[dst, ah, aj*4 .. aj*4+4)
__global__ __launch_bounds__(256) void fused_attn(
    const float* __restrict__ q, const ushort* __restrict__ k,
    const ushort* __restrict__ v, const int* __restrict__ col,
    const int* __restrict__ row_ptr, float* __restrict__ agg, int n)
{
    int node = blockIdx.x * 4 + (threadIdx.x >> 6);
    if (node >= n) return;
    int lane = threadIdx.x & 63;
    int p0 = row_ptr[node], p1 = row_ptr[node + 1];

    const int slot = lane >> 3;   // score phase: edge slot
    const int sh   = lane & 7;    // score phase: head
    const int ah   = lane >> 3;   // accum phase: head
    const int aj   = lane & 7;    // accum phase: dim quad

    // q[dst, sh, :] in registers (32 floats)
    float qf[32];
    {
        const float4* qp = (const float4*)(q + (size_t)node * 256 + sh * 32);
        #pragma unroll
        for (int i = 0; i < 8; ++i) {
            float4 t = qp[i];
            qf[4 * i + 0] = t.x; qf[4 * i + 1] = t.y;
            qf[4 * i + 2] = t.z; qf[4 * i + 3] = t.w;
        }
    }

    float m_run = -INFINITY;   // running max, head ah
    float denom = 0.f;
    float acc0 = 0.f, acc1 = 0.f, acc2 = 0.f, acc3 = 0.f;

    for (int base = p0; base < p1; base += 8) {
        // ---- score phase ----
        int e = base + slot;
        bool valid = e < p1;
        int src = valid ? col[e] : 0;
        float s = -INFINITY;
        if (valid) {
            const uint4* kp = (const uint4*)(k + (size_t)src * 256 + sh * 32);
            float sacc = 0.f;
            #pragma unroll
            for (int i = 0; i < 4; ++i) {
                uint4 kk = kp[i];
                sacc += qf[8*i+0] * bflo(kk.x) + qf[8*i+1] * bfhi(kk.x);
                sacc += qf[8*i+2] * bflo(kk.y) + qf[8*i+3] * bfhi(kk.y);
                sacc += qf[8*i+4] * bflo(kk.z) + qf[8*i+5] * bfhi(kk.z);
                sacc += qf[8*i+6] * bflo(kk.w) + qf[8*i+7] * bfhi(kk.w);
            }
            s = sacc;
        }

        // chunk max per head sh (reduce across slot bits 3..5)
        float mc = s;
        mc = fmaxf(mc, __shfl_xor(mc, 8));
        mc = fmaxf(mc, __shfl_xor(mc, 16));
        mc = fmaxf(mc, __shfl_xor(mc, 32));
        // fetch chunk max for accum head ah (lane ah has slot=0, sh=ah)
        float mc_a = __shfl(mc, ah);

        // ---- online rescale (accum layout) ----
        float m_new = fmaxf(m_run, mc_a);
        float rescale = __expf(m_run - m_new);  // exp(-inf)=0 on first chunk
        denom *= rescale;
        acc0 *= rescale; acc1 *= rescale; acc2 *= rescale; acc3 *= rescale;
        m_run = m_new;

        // ---- accum phase ----
        int nvalid = min(8, p1 - base);
        for (int ee = 0; ee < nvalid; ++ee) {
            float se = __shfl(s, (ee << 3) + ah);
            float pe = __expf(se - m_new);
            denom += pe;
            int src_e = __shfl(src, ee << 3);
            uint2 vv = *(const uint2*)(v + (size_t)src_e * 256 + ah * 32 + aj * 4);
            acc0 = fmaf(pe, bflo(vv.x), acc0);
            acc1 = fmaf(pe, bfhi(vv.x), acc1);
            acc2 = fmaf(pe, bflo(vv.y), acc2);
            acc3 = fmaf(pe, bfhi(vv.y), acc3);
        }
    }

    float inv = denom > 0.f ? 1.f / denom : 0.f;
    *(float4*)(agg + (size_t)node * 256 + (lane << 2)) =
        make_float4(acc0 * inv, acc1 * inv, acc2 * inv, acc3 * inv);
}

extern "C" void kernel_launch(void* const* d_in, const int* in_sizes, int n_in,
                              void* d_out, int out_size, void* d_ws, size_t ws_size,
                              hipStream_t stream)
{
    const float* h  = (const float*)d_in[0];
    const int*   row = (const int*)d_in[1];
    const int*   col = (const int*)d_in[2];
    const float* Wq = (const float*)d_in[3];
    const float* bq = (const float*)d_in[4];
    const float* Wk = (const float*)d_in[5];
    const float* bk = (const float*)d_in[6];
    const float* Wv = (const float*)d_in[7];
    const float* bv = (const float*)d_in[8];
    const float* Wo = (const float*)d_in[9];
    const float* bo = (const float*)d_in[10];
    float* out = (float*)d_out;

    const int n = in_sizes[0] / 256;
    const int E = in_sizes[1];
    const size_t NC = (size_t)n * 256;

    char* base = (char*)d_ws;
    float*  q   = (float*)(base);             // NC * 4 bytes
    ushort* kb  = (ushort*)(base + NC * 4);   // NC * 2
    ushort* vb  = (ushort*)(base + NC * 6);   // NC * 2
    float*  agg = (float*)(base + NC * 8);    // NC * 4
    int* row_ptr = (int*)(base + NC * 12);    // (n+1) * 4

    const float scaling = 0.17677669529663687f;  // 32^-0.5

    dim3 gblk(256);
    dim3 ggrid((n + 63) / 64, 4);
    gemm_tile<false><<<ggrid, gblk, 0, stream>>>(h, Wq, bq, q,  n, scaling);
    gemm_tile<true ><<<ggrid, gblk, 0, stream>>>(h, Wk, bk, kb, n, 1.f);
    gemm_tile<true ><<<ggrid, gblk, 0, stream>>>(h, Wv, bv, vb, n, 1.f);

    build_row_ptr<<<dim3((n + 256) / 256), gblk, 0, stream>>>(row, row_ptr, n, E);

    fused_attn<<<dim3((n + 3) / 4), gblk, 0, stream>>>(
        q, kb, vb, col, row_ptr, agg, n);

    gemm_tile<false><<<ggrid, gblk, 0, stream>>>(agg, Wo, bo, out, n, 1.f);
}

// Round 3
// 372.961 us; speedup vs baseline: 1.8446x; 1.4494x over previous
//
#include <hip/hip_runtime.h>
#include <math.h>

// ---------------------------------------------------------------------------
// SparseMHA with bf16 MFMA projections:
//   hb = bf16(h); Wxt = bf16(Wx^T)
//   q = (hb@Wq+bq)*scale (f32) ; kb = hb@Wk+bk (bf16) ; vb = hb@Wv+bv (bf16)
//   fused per-dst-node online-softmax attention -> aggb (bf16)
//   out = aggb @ Wo + bo (f32)
// ---------------------------------------------------------------------------

typedef __attribute__((ext_vector_type(8))) short bf16x8;   // 8 bf16 = 4 VGPR
typedef __attribute__((ext_vector_type(4))) float f32x4;

__device__ __forceinline__ ushort f2bf(float f) {           // RNE f32->bf16
    uint u = __float_as_uint(f);
    u += 0x7fffu + ((u >> 16) & 1u);
    return (ushort)(u >> 16);
}
__device__ __forceinline__ float bflo(uint u) { return __uint_as_float(u << 16); }
__device__ __forceinline__ float bfhi(uint u) { return __uint_as_float(u & 0xffff0000u); }

// f32 -> bf16 elementwise (h)
__global__ __launch_bounds__(256) void convert_bf16(
    const float* __restrict__ in, ushort* __restrict__ out, size_t nelem)
{
    size_t i = ((size_t)blockIdx.x * 256 + threadIdx.x) * 4;
    if (i >= nelem) return;
    float4 v = *(const float4*)(in + i);
    ushort4 o = make_ushort4(f2bf(v.x), f2bf(v.y), f2bf(v.z), f2bf(v.w));
    *(ushort4*)(out + i) = o;
}

// W[256x256] f32 -> W^T bf16
__global__ __launch_bounds__(256) void convert_wt(
    const float* __restrict__ W, ushort* __restrict__ Wt)
{
    int idx = blockIdx.x * 256 + threadIdx.x;   // idx = k*256 + n
    int k = idx >> 8, n = idx & 255;
    Wt[n * 256 + k] = f2bf(W[idx]);
}

// MFMA GEMM: C[n x 256] = A_bf16[n x 256] @ Wt_bf16[256 x 256]^T' (+bias)*scale
// Wt is N-major (Wt[n][k] = W[k][n]). Block = 4 waves, each wave 64x64 tile.
// No LDS: A frags from global (L1/L3-cached), B frags from global (L2-resident).
template<bool BF16OUT>
__global__ __launch_bounds__(256) void gemm_mfma(
    const ushort* __restrict__ A, const ushort* __restrict__ Wt,
    const float* __restrict__ bias, void* __restrict__ Cout,
    int n, float scale)
{
    const int lane = threadIdx.x & 63;
    const int wave = threadIdx.x >> 6;
    const int row0 = blockIdx.x * 256 + wave * 64;   // wave's first A row
    const int col0 = blockIdx.y * 64;                // block's first C col

    const int fr = lane & 15;          // frag row (A) / col (B,D)
    const int kg = lane >> 4;          // k-group: k = kg*8 .. kg*8+7

    f32x4 acc[4][4] = {};

    #pragma unroll 2
    for (int ks = 0; ks < 8; ++ks) {
        const int kofs = ks * 32 + kg * 8;
        bf16x8 a[4], b[4];
        #pragma unroll
        for (int i = 0; i < 4; ++i) {
            int r = row0 + i * 16 + fr;
            r = r < n ? r : n - 1;   // clamp: garbage rows never stored
            a[i] = *(const bf16x8*)(A + (size_t)r * 256 + kofs);
        }
        #pragma unroll
        for (int j = 0; j < 4; ++j) {
            int c = col0 + j * 16 + fr;
            b[j] = *(const bf16x8*)(Wt + (size_t)c * 256 + kofs);
        }
        #pragma unroll
        for (int i = 0; i < 4; ++i)
            #pragma unroll
            for (int j = 0; j < 4; ++j)
                acc[i][j] = __builtin_amdgcn_mfma_f32_16x16x32_bf16(
                    a[i], b[j], acc[i][j], 0, 0, 0);
    }

    // D: col = lane&15, row = (lane>>4)*4 + r
    #pragma unroll
    for (int j = 0; j < 4; ++j) {
        int gcol = col0 + j * 16 + fr;
        float bj = bias[gcol];
        #pragma unroll
        for (int i = 0; i < 4; ++i) {
            #pragma unroll
            for (int r = 0; r < 4; ++r) {
                int grow = row0 + i * 16 + kg * 4 + r;
                if (grow >= n) continue;
                float ov = (acc[i][j][r] + bj) * scale;
                if constexpr (BF16OUT)
                    ((ushort*)Cout)[(size_t)grow * 256 + gcol] = f2bf(ov);
                else
                    ((float*)Cout)[(size_t)grow * 256 + gcol] = ov;
            }
        }
    }
}

// CSR row pointers from sorted row[]: row_ptr[i] = lower_bound(row, i)
__global__ __launch_bounds__(256) void build_row_ptr(
    const int* __restrict__ row, int* __restrict__ row_ptr, int n, int E)
{
    int i = blockIdx.x * 256 + threadIdx.x;
    if (i > n) return;
    int lo = 0, hi = E;
    while (lo < hi) {
        int mid = (lo + hi) >> 1;
        if (row[mid] < i) lo = mid + 1; else hi = mid;
    }
    row_ptr[i] = lo;
}

// Fused SDDMM + online softmax + SpMM. One wave per dst node. agg out = bf16.
__global__ __launch_bounds__(256) void fused_attn(
    const float* __restrict__ q, const ushort* __restrict__ k,
    const ushort* __restrict__ v, const int* __restrict__ col,
    const int* __restrict__ row_ptr, ushort* __restrict__ agg, int n)
{
    int node = blockIdx.x * 4 + (threadIdx.x >> 6);
    if (node >= n) return;
    int lane = threadIdx.x & 63;
    int p0 = row_ptr[node], p1 = row_ptr[node + 1];

    const int slot = lane >> 3;   // score phase: edge slot
    const int sh   = lane & 7;    // score phase: head
    const int ah   = lane >> 3;   // accum phase: head
    const int aj   = lane & 7;    // accum phase: dim quad

    float qf[32];
    {
        const float4* qp = (const float4*)(q + (size_t)node * 256 + sh * 32);
        #pragma unroll
        for (int i = 0; i < 8; ++i) {
            float4 t = qp[i];
            qf[4 * i + 0] = t.x; qf[4 * i + 1] = t.y;
            qf[4 * i + 2] = t.z; qf[4 * i + 3] = t.w;
        }
    }

    float m_run = -INFINITY;
    float denom = 0.f;
    float acc0 = 0.f, acc1 = 0.f, acc2 = 0.f, acc3 = 0.f;

    for (int base = p0; base < p1; base += 8) {
        int e = base + slot;
        bool valid = e < p1;
        int src = valid ? col[e] : 0;
        float s = -INFINITY;
        if (valid) {
            const uint4* kp = (const uint4*)(k + (size_t)src * 256 + sh * 32);
            float sacc = 0.f;
            #pragma unroll
            for (int i = 0; i < 4; ++i) {
                uint4 kk = kp[i];
                sacc += qf[8*i+0] * bflo(kk.x) + qf[8*i+1] * bfhi(kk.x);
                sacc += qf[8*i+2] * bflo(kk.y) + qf[8*i+3] * bfhi(kk.y);
                sacc += qf[8*i+4] * bflo(kk.z) + qf[8*i+5] * bfhi(kk.z);
                sacc += qf[8*i+6] * bflo(kk.w) + qf[8*i+7] * bfhi(kk.w);
            }
            s = sacc;
        }

        float mc = s;
        mc = fmaxf(mc, __shfl_xor(mc, 8));
        mc = fmaxf(mc, __shfl_xor(mc, 16));
        mc = fmaxf(mc, __shfl_xor(mc, 32));
        float mc_a = __shfl(mc, ah);

        float m_new = fmaxf(m_run, mc_a);
        float rescale = __expf(m_run - m_new);
        denom *= rescale;
        acc0 *= rescale; acc1 *= rescale; acc2 *= rescale; acc3 *= rescale;
        m_run = m_new;

        int nvalid = min(8, p1 - base);
        for (int ee = 0; ee < nvalid; ++ee) {
            float se = __shfl(s, (ee << 3) + ah);
            float pe = __expf(se - m_new);
            denom += pe;
            int src_e = __shfl(src, ee << 3);
            uint2 vv = *(const uint2*)(v + (size_t)src_e * 256 + ah * 32 + aj * 4);
            acc0 = fmaf(pe, bflo(vv.x), acc0);
            acc1 = fmaf(pe, bfhi(vv.x), acc1);
            acc2 = fmaf(pe, bflo(vv.y), acc2);
            acc3 = fmaf(pe, bfhi(vv.y), acc3);
        }
    }

    float inv = denom > 0.f ? 1.f / denom : 0.f;
    ushort4 o = make_ushort4(f2bf(acc0 * inv), f2bf(acc1 * inv),
                             f2bf(acc2 * inv), f2bf(acc3 * inv));
    *(ushort4*)(agg + (size_t)node * 256 + (lane << 2)) = o;
}

extern "C" void kernel_launch(void* const* d_in, const int* in_sizes, int n_in,
                              void* d_out, int out_size, void* d_ws, size_t ws_size,
                              hipStream_t stream)
{
    const float* h  = (const float*)d_in[0];
    const int*   row = (const int*)d_in[1];
    const int*   col = (const int*)d_in[2];
    const float* Wq = (const float*)d_in[3];
    const float* bq = (const float*)d_in[4];
    const float* Wk = (const float*)d_in[5];
    const float* bk = (const float*)d_in[6];
    const float* Wv = (const float*)d_in[7];
    const float* bv = (const float*)d_in[8];
    const float* Wo = (const float*)d_in[9];
    const float* bo = (const float*)d_in[10];
    float* out = (float*)d_out;

    const int n = in_sizes[0] / 256;
    const int E = in_sizes[1];
    const size_t NC = (size_t)n * 256;

    char* base = (char*)d_ws;
    ushort* hb   = (ushort*)(base);               // NC*2
    float*  q    = (float*)(base + NC * 2);       // NC*4
    ushort* kb   = (ushort*)(base + NC * 6);      // NC*2
    ushort* vb   = (ushort*)(base + NC * 8);      // NC*2
    ushort* aggb = (ushort*)(base + NC * 10);     // NC*2
    ushort* Wqt  = (ushort*)(base + NC * 12);     // 128KB each
    ushort* Wkt  = Wqt + 65536;
    ushort* Wvt  = Wkt + 65536;
    ushort* Wot  = Wvt + 65536;
    int* row_ptr = (int*)(Wot + 65536);

    const float scaling = 0.17677669529663687f;  // 32^-0.5

    dim3 blk(256);
    convert_bf16<<<dim3((int)((NC / 4 + 255) / 256)), blk, 0, stream>>>(h, hb, NC);
    convert_wt<<<dim3(256), blk, 0, stream>>>(Wq, Wqt);
    convert_wt<<<dim3(256), blk, 0, stream>>>(Wk, Wkt);
    convert_wt<<<dim3(256), blk, 0, stream>>>(Wv, Wvt);
    convert_wt<<<dim3(256), blk, 0, stream>>>(Wo, Wot);

    dim3 ggrid((n + 255) / 256, 4);
    gemm_mfma<false><<<ggrid, blk, 0, stream>>>(hb, Wqt, bq, q,  n, scaling);
    gemm_mfma<true ><<<ggrid, blk, 0, stream>>>(hb, Wkt, bk, kb, n, 1.f);
    gemm_mfma<true ><<<ggrid, blk, 0, stream>>>(hb, Wvt, bv, vb, n, 1.f);

    build_row_ptr<<<dim3((n + 256) / 256), blk, 0, stream>>>(row, row_ptr, n, E);

    fused_attn<<<dim3((n + 3) / 4), blk, 0, stream>>>(
        q, kb, vb, col, row_ptr, aggb, n);

    gemm_mfma<false><<<ggrid, blk, 0, stream>>>(aggb, Wot, bo, out, n, 1.f);
}

// Round 4
// 228.265 us; speedup vs baseline: 3.0138x; 1.6339x over previous
//
#include <hip/hip_runtime.h>
#include <math.h>

// ---------------------------------------------------------------------------
// SparseMHA, round 4:
//   hb = bf16(h)
//   qkv[n][768] bf16 = one fused MFMA GEMM (q scaled) ; LDS-staged 128x128
//   fused per-dst-node online-softmax attention (k-prefetch, unrolled accum)
//   out = aggb @ Wo + bo (f32), same GEMM structure
// ---------------------------------------------------------------------------

typedef __attribute__((ext_vector_type(8))) short bf16x8;
typedef __attribute__((ext_vector_type(4))) float f32x4;

__device__ __forceinline__ ushort f2bf(float f) {           // RNE f32->bf16
    uint u = __float_as_uint(f);
    u += 0x7fffu + ((u >> 16) & 1u);
    return (ushort)(u >> 16);
}
__device__ __forceinline__ float bflo(uint u) { return __uint_as_float(u << 16); }
__device__ __forceinline__ float bfhi(uint u) { return __uint_as_float(u & 0xffff0000u); }

__device__ __forceinline__ void load_lds16(const void* g, void* l) {
    __builtin_amdgcn_global_load_lds(
        (const __attribute__((address_space(1))) void*)g,
        (__attribute__((address_space(3))) void*)l, 16, 0, 0);
}

// f32 -> bf16 elementwise (h)
__global__ __launch_bounds__(256) void convert_bf16(
    const float* __restrict__ in, ushort* __restrict__ out, size_t nelem)
{
    size_t i = ((size_t)blockIdx.x * 256 + threadIdx.x) * 4;
    if (i >= nelem) return;
    float4 v = *(const float4*)(in + i);
    *(ushort4*)(out + i) = make_ushort4(f2bf(v.x), f2bf(v.y), f2bf(v.z), f2bf(v.w));
}

// Wq,Wk,Wv [256x256] f32 -> concat W^T bf16 [768][256]
__global__ __launch_bounds__(256) void convert_wt3(
    const float* __restrict__ Wq, const float* __restrict__ Wk,
    const float* __restrict__ Wv, ushort* __restrict__ Wall)
{
    int m = blockIdx.y;
    const float* W = m == 0 ? Wq : (m == 1 ? Wk : Wv);
    int idx = blockIdx.x * 256 + threadIdx.x;   // idx = k*256 + nn
    int k = idx >> 8, nn = idx & 255;
    Wall[((size_t)m * 256 + nn) * 256 + k] = f2bf(W[idx]);
}

__global__ __launch_bounds__(256) void convert_wt1(
    const float* __restrict__ W, ushort* __restrict__ Wt)
{
    int idx = blockIdx.x * 256 + threadIdx.x;
    int k = idx >> 8, nn = idx & 255;
    Wt[nn * 256 + k] = f2bf(W[idx]);
}

__global__ __launch_bounds__(256) void concat_bias(
    const float* __restrict__ bq, const float* __restrict__ bk,
    const float* __restrict__ bv, float* __restrict__ ball)
{
    int i = blockIdx.x * 256 + threadIdx.x;
    if (i >= 768) return;
    ball[i] = i < 256 ? bq[i] : (i < 512 ? bk[i - 256] : bv[i - 512]);
}

// ---------------------------------------------------------------------------
// LDS-staged MFMA GEMM (m97 structure): C[n x NCOLS] = A[n x 256] @ Wt^T
// BM=128, BN=128, BK=64, 4 waves (2x2 of 64x64), global_load_lds width 16,
// XOR-swizzled LDS (chunk ^ row&7 within 128B rows), 2 barriers per K-tile.
// MODE 0: store bf16 into qkv[n][768] (cols<256 scaled). MODE 1: f32 out.
// ---------------------------------------------------------------------------
template<int MODE>
__global__ __launch_bounds__(256) void gemm_mfma_lds(
    const ushort* __restrict__ A, const ushort* __restrict__ Wt,
    const float* __restrict__ bias, ushort* __restrict__ qkv,
    float* __restrict__ outf, int n, float scale)
{
    __shared__ ushort As[128 * 64];   // [row][64k], row stride 128B, swizzled
    __shared__ ushort Bs[128 * 64];

    // bijective XCD swizzle (m204)
    const int nwg = gridDim.x * gridDim.y;
    const int orig = blockIdx.y * gridDim.x + blockIdx.x;
    const int xcd = orig & 7, rnd = orig >> 3;
    const int q8 = nwg >> 3, r8 = nwg & 7;
    const int wgid = (xcd < r8 ? xcd * (q8 + 1) : r8 * (q8 + 1) + (xcd - r8) * q8) + rnd;
    const int tx = wgid % gridDim.x;        // col tile
    const int ty = wgid / gridDim.x;        // row tile

    const int tid = threadIdx.x;
    const int lane = tid & 63;
    const int wave = tid >> 6;
    const int col0 = tx * 128;
    const int row0 = ty * 128;
    const int fr = lane & 15;
    const int kg = lane >> 4;
    const int wr = (wave >> 1) * 64;
    const int wc = (wave & 1) * 64;

    f32x4 acc[4][4] = {};

    const int srow = tid >> 3;     // staging row (+ it*32)
    const int sc8 = tid & 7;       // staging 16B-chunk within 128B row

    for (int kt = 0; kt < 4; ++kt) {
        #pragma unroll
        for (int it = 0; it < 4; ++it) {
            int r = srow + it * 32;
            int chunk = sc8 ^ (r & 7);
            int ar = row0 + r; ar = ar < n ? ar : n - 1;
            load_lds16((const char*)A + (size_t)ar * 512 + kt * 128 + chunk * 16,
                       (char*)As + (it * 256 + tid) * 16);
            load_lds16((const char*)Wt + (size_t)(col0 + r) * 512 + kt * 128 + chunk * 16,
                       (char*)Bs + (it * 256 + tid) * 16);
        }
        __syncthreads();

        #pragma unroll
        for (int ks = 0; ks < 2; ++ks) {
            bf16x8 a[4], b[4];
            #pragma unroll
            for (int i = 0; i < 4; ++i) {
                int r = wr + i * 16 + fr;
                int chunk = (ks * 4 + kg) ^ (r & 7);
                a[i] = *(const bf16x8*)((const char*)As + r * 128 + chunk * 16);
            }
            #pragma unroll
            for (int j = 0; j < 4; ++j) {
                int c = wc + j * 16 + fr;
                int chunk = (ks * 4 + kg) ^ (c & 7);
                b[j] = *(const bf16x8*)((const char*)Bs + c * 128 + chunk * 16);
            }
            #pragma unroll
            for (int i = 0; i < 4; ++i)
                #pragma unroll
                for (int j = 0; j < 4; ++j)
                    acc[i][j] = __builtin_amdgcn_mfma_f32_16x16x32_bf16(
                        a[i], b[j], acc[i][j], 0, 0, 0);
        }
        __syncthreads();
    }

    // D layout: col = lane&15 (fr), row = kg*4 + r
    #pragma unroll
    for (int j = 0; j < 4; ++j) {
        int gcol = col0 + wc + j * 16 + fr;
        float bj = bias[gcol];
        float sc = (MODE == 0 && gcol < 256) ? scale : 1.f;
        #pragma unroll
        for (int i = 0; i < 4; ++i) {
            #pragma unroll
            for (int r = 0; r < 4; ++r) {
                int grow = row0 + wr + i * 16 + kg * 4 + r;
                if (grow >= n) continue;
                float val = (acc[i][j][r] + bj) * sc;
                if constexpr (MODE == 0)
                    qkv[(size_t)grow * 768 + gcol] = f2bf(val);
                else
                    outf[(size_t)grow * 256 + gcol] = val;
            }
        }
    }
}

// CSR row pointers from sorted row[]: row_ptr[i] = lower_bound(row, i)
__global__ __launch_bounds__(256) void build_row_ptr(
    const int* __restrict__ row, int* __restrict__ row_ptr, int n, int E)
{
    int i = blockIdx.x * 256 + threadIdx.x;
    if (i > n) return;
    int lo = 0, hi = E;
    while (lo < hi) {
        int mid = (lo + hi) >> 1;
        if (row[mid] < i) lo = mid + 1; else hi = mid;
    }
    row_ptr[i] = lo;
}

// Fused SDDMM + online softmax + SpMM over qkv[n][768] bf16.
// One wave per dst node. k-prefetch of next chunk; unrolled full-8 accum.
__global__ __launch_bounds__(256) void fused_attn(
    const ushort* __restrict__ qkv, const int* __restrict__ col,
    const int* __restrict__ row_ptr, ushort* __restrict__ agg, int n)
{
    int node = blockIdx.x * 4 + (threadIdx.x >> 6);
    if (node >= n) return;
    int lane = threadIdx.x & 63;
    int p0 = row_ptr[node], p1 = row_ptr[node + 1];

    const int slot = lane >> 3;   // score phase: edge slot
    const int sh   = lane & 7;    // score phase: head
    const int ah   = lane >> 3;   // accum phase: head
    const int aj   = lane & 7;    // accum phase: dim quad

    // q[node, sh, :] -> 32 floats
    float qf[32];
    {
        const uint4* qp = (const uint4*)(qkv + (size_t)node * 768 + sh * 32);
        #pragma unroll
        for (int i = 0; i < 4; ++i) {
            uint4 t = qp[i];
            qf[8*i+0] = bflo(t.x); qf[8*i+1] = bfhi(t.x);
            qf[8*i+2] = bflo(t.y); qf[8*i+3] = bfhi(t.y);
            qf[8*i+4] = bflo(t.z); qf[8*i+5] = bfhi(t.z);
            qf[8*i+6] = bflo(t.w); qf[8*i+7] = bfhi(t.w);
        }
    }

    float m_run = -INFINITY;
    float denom = 0.f;
    float acc0 = 0.f, acc1 = 0.f, acc2 = 0.f, acc3 = 0.f;

    // prefetched k-chunk state
    bool valid = false; int src = 0;
    uint4 kk[4];
    {
        int e = p0 + slot;
        valid = e < p1;
        src = valid ? col[e] : 0;
        if (valid) {
            const uint4* kp = (const uint4*)(qkv + (size_t)src * 768 + 256 + sh * 32);
            kk[0] = kp[0]; kk[1] = kp[1]; kk[2] = kp[2]; kk[3] = kp[3];
        }
    }

    for (int base = p0; base < p1; base += 8) {
        // ---- scores from prefetched k ----
        float s = -INFINITY;
        if (valid) {
            float sacc = 0.f;
            #pragma unroll
            for (int i = 0; i < 4; ++i) {
                sacc += qf[8*i+0] * bflo(kk[i].x) + qf[8*i+1] * bfhi(kk[i].x);
                sacc += qf[8*i+2] * bflo(kk[i].y) + qf[8*i+3] * bfhi(kk[i].y);
                sacc += qf[8*i+4] * bflo(kk[i].z) + qf[8*i+5] * bfhi(kk[i].z);
                sacc += qf[8*i+6] * bflo(kk[i].w) + qf[8*i+7] * bfhi(kk[i].w);
            }
            s = sacc;
        }
        int src_c = src;

        // ---- prefetch next chunk's k (flies under accum) ----
        if (base + 8 < p1) {
            int e = base + 8 + slot;
            valid = e < p1;
            src = valid ? col[e] : 0;
            if (valid) {
                const uint4* kp = (const uint4*)(qkv + (size_t)src * 768 + 256 + sh * 32);
                kk[0] = kp[0]; kk[1] = kp[1]; kk[2] = kp[2]; kk[3] = kp[3];
            }
        }

        // ---- chunk max per head, online rescale ----
        float mc = s;
        mc = fmaxf(mc, __shfl_xor(mc, 8));
        mc = fmaxf(mc, __shfl_xor(mc, 16));
        mc = fmaxf(mc, __shfl_xor(mc, 32));
        float mc_a = __shfl(mc, ah);

        float m_new = fmaxf(m_run, mc_a);
        float rescale = __expf(m_run - m_new);
        denom *= rescale;
        acc0 *= rescale; acc1 *= rescale; acc2 *= rescale; acc3 *= rescale;
        m_run = m_new;

        // ---- accum ----
        int nvalid = min(8, p1 - base);
        if (nvalid == 8) {
            float se[8]; int srcs[8];
            #pragma unroll
            for (int ee = 0; ee < 8; ++ee) {
                se[ee] = __shfl(s, (ee << 3) + ah);
                srcs[ee] = __shfl(src_c, ee << 3);
            }
            uint2 vv[8];
            #pragma unroll
            for (int ee = 0; ee < 8; ++ee)
                vv[ee] = *(const uint2*)(qkv + (size_t)srcs[ee] * 768 + 512 + ah * 32 + (aj << 2));
            #pragma unroll
            for (int ee = 0; ee < 8; ++ee) {
                float pe = __expf(se[ee] - m_new);
                denom += pe;
                acc0 = fmaf(pe, bflo(vv[ee].x), acc0);
                acc1 = fmaf(pe, bfhi(vv[ee].x), acc1);
                acc2 = fmaf(pe, bflo(vv[ee].y), acc2);
                acc3 = fmaf(pe, bfhi(vv[ee].y), acc3);
            }
        } else {
            for (int ee = 0; ee < nvalid; ++ee) {
                float se = __shfl(s, (ee << 3) + ah);
                float pe = __expf(se - m_new);
                denom += pe;
                int src_e = __shfl(src_c, ee << 3);
                uint2 vv = *(const uint2*)(qkv + (size_t)src_e * 768 + 512 + ah * 32 + (aj << 2));
                acc0 = fmaf(pe, bflo(vv.x), acc0);
                acc1 = fmaf(pe, bfhi(vv.x), acc1);
                acc2 = fmaf(pe, bflo(vv.y), acc2);
                acc3 = fmaf(pe, bfhi(vv.y), acc3);
            }
        }
    }

    float inv = denom > 0.f ? 1.f / denom : 0.f;
    ushort4 o = make_ushort4(f2bf(acc0 * inv), f2bf(acc1 * inv),
                             f2bf(acc2 * inv), f2bf(acc3 * inv));
    *(ushort4*)(agg + (size_t)node * 256 + (lane << 2)) = o;
}

extern "C" void kernel_launch(void* const* d_in, const int* in_sizes, int n_in,
                              void* d_out, int out_size, void* d_ws, size_t ws_size,
                              hipStream_t stream)
{
    const float* h  = (const float*)d_in[0];
    const int*   row = (const int*)d_in[1];
    const int*   col = (const int*)d_in[2];
    const float* Wq = (const float*)d_in[3];
    const float* bq = (const float*)d_in[4];
    const float* Wk = (const float*)d_in[5];
    const float* bk = (const float*)d_in[6];
    const float* Wv = (const float*)d_in[7];
    const float* bv = (const float*)d_in[8];
    const float* Wo = (const float*)d_in[9];
    const float* bo = (const float*)d_in[10];
    float* out = (float*)d_out;

    const int n = in_sizes[0] / 256;
    const int E = in_sizes[1];
    const size_t NC = (size_t)n * 256;

    char* base = (char*)d_ws;
    ushort* qkvb = (ushort*)(base);                 // NC*3 ushort = NC*6 B
    ushort* hb   = (ushort*)(base + NC * 6);        // NC*2
    ushort* aggb = (ushort*)(base + NC * 8);        // NC*2
    ushort* Wall = (ushort*)(base + NC * 10);       // 768*256*2 = 384KB
    ushort* Wot  = Wall + 768 * 256;                // 128KB
    float*  ball = (float*)(Wot + 65536);           // 3KB
    int* row_ptr = (int*)(ball + 768);

    const float scaling = 0.17677669529663687f;  // 32^-0.5

    dim3 blk(256);
    convert_bf16<<<dim3((int)((NC / 4 + 255) / 256)), blk, 0, stream>>>(h, hb, NC);
    convert_wt3<<<dim3(256, 3), blk, 0, stream>>>(Wq, Wk, Wv, Wall);
    convert_wt1<<<dim3(256), blk, 0, stream>>>(Wo, Wot);
    concat_bias<<<dim3(3), blk, 0, stream>>>(bq, bk, bv, ball);
    build_row_ptr<<<dim3((n + 256) / 256), blk, 0, stream>>>(row, row_ptr, n, E);

    const int mtiles = (n + 127) / 128;
    gemm_mfma_lds<0><<<dim3(6, mtiles), blk, 0, stream>>>(
        hb, Wall, ball, qkvb, nullptr, n, scaling);

    fused_attn<<<dim3((n + 3) / 4), blk, 0, stream>>>(
        qkvb, col, row_ptr, aggb, n);

    gemm_mfma_lds<1><<<dim3(2, mtiles), blk, 0, stream>>>(
        aggb, Wot, bo, nullptr, out, n, 1.f);
}